// Round 2
// baseline (50.352 us; speedup 1.0000x reference)
//
#include <hip/hip_runtime.h>

#define IMG_W 256
#define IMG_H 256
#define EPSN 1e-7f
#define SIG2 0.02f          // 2 * 0.1^2
#define NB 16               // batch
#define NN 64               // strokes per image
#define NC 3                // channels
#define PH 32
#define PW 32
#define WIN 36              // stroke footprint window (see analysis)

// ---------------- kernel 1: per-image min/max normalization ----------------
__global__ __launch_bounds__(64)
void norm_kernel(const float* __restrict__ brushes, float* __restrict__ gxy) {
    int b = blockIdx.x;
    int n = threadIdx.x;          // one wave == 64 lanes == N strokes
    float x = brushes[(b * NN + n) * 2 + 0];
    float y = brushes[(b * NN + n) * 2 + 1];
    float mnx = x, mxx = x, mny = y, mxy = y;
    #pragma unroll
    for (int off = 32; off > 0; off >>= 1) {
        mnx = fminf(mnx, __shfl_xor(mnx, off));
        mxx = fmaxf(mxx, __shfl_xor(mxx, off));
        mny = fminf(mny, __shfl_xor(mny, off));
        mxy = fmaxf(mxy, __shfl_xor(mxy, off));
    }
    float gx = (x - mnx) / (mxx - mnx + EPSN) * (float)IMG_W;
    float gy = (y - mny) / (mxy - mny + EPSN) * (float)IMG_H;
    gxy[(b * NN + n) * 2 + 0] = gx;
    gxy[(b * NN + n) * 2 + 1] = gy;
}

// ---------------- kernel 2: one block per stroke, splat 36x36 window --------
__global__ __launch_bounds__(256)
void stroke_kernel(const float* __restrict__ patches,
                   const float* __restrict__ gxy,
                   float* __restrict__ out) {
    __shared__ float patch_s[NC][PH][PW + 1];   // +1 pad: kill stride-32 conflicts
    __shared__ float fx_s[WIN][PW + 1];         // [x_local][q]
    __shared__ float fy_s[WIN][PH + 1];         // [y_local][p]
    __shared__ float t_s[NC][WIN][PH + 1];      // [c][x_local][p]
    __shared__ float den_x[PW], den_y[PH];

    const int blk = blockIdx.x;                 // stroke index b*64+n
    const int tid = threadIdx.x;
    const float* P = patches + (size_t)blk * (NC * PH * PW);

    const float gx = gxy[blk * 2 + 0];
    const float gy = gxy[blk * 2 + 1];
    const int ix0 = (int)floorf(gx) - 17;       // window covers all nonzero taps
    const int iy0 = (int)floorf(gy) - 17;

    // --- stage A: patch -> LDS (float4 coalesced) ---
    for (int i = tid; i < NC * PH * PW / 4; i += 256) {
        float4 v = ((const float4*)P)[i];
        int base = i * 4;
        int c = base / (PH * PW);
        int r = base - c * (PH * PW);
        int p = r >> 5, q = r & 31;
        patch_s[c][p][q + 0] = v.x;
        patch_s[c][p][q + 1] = v.y;
        patch_s[c][p][q + 2] = v.z;
        patch_s[c][p][q + 3] = v.w;
    }

    // --- stage B1: normalization denominators (4 taps capture all nonzero f32 terms) ---
    if (tid < PW) {
        float cx = gx + (float)tid - 15.5f;     // ux_q = gx + (q+1) - 16.5
        int f = (int)floorf(cx);
        float s = 0.f;
        #pragma unroll
        for (int t = -1; t <= 2; ++t) {
            int a = f + t;
            if (a >= -16 && a <= IMG_W + 15) {  // reference sums a in [-16, 271]
                float d = (float)a - cx;
                s += expf(-(d * d) / SIG2);
            }
        }
        den_x[tid] = 1.f / (s + EPSN);
    } else if (tid < 2 * PW) {
        int p = tid - PW;
        float cy = gy + (float)p - 15.4f;       // uy_p = gy + (p+1) - 16.4
        int f = (int)floorf(cy);
        float s = 0.f;
        #pragma unroll
        for (int t = -1; t <= 2; ++t) {
            int a = f + t;
            if (a >= -16 && a <= IMG_H + 15) {
                float d = (float)a - cy;
                s += expf(-(d * d) / SIG2);
            }
        }
        den_y[p] = 1.f / (s + EPSN);
    }
    __syncthreads();

    // --- stage B2: Fx, Fy windows ---
    for (int i = tid; i < WIN * PW; i += 256) {
        int xl = i >> 5, q = i & 31;
        float cx = gx + (float)q - 15.5f;
        float d = (float)(ix0 + xl) - cx;
        fx_s[xl][q] = expf(-(d * d) / SIG2) * den_x[q];
    }
    for (int i = tid; i < WIN * PH; i += 256) {
        int yl = i >> 5, p = i & 31;
        float cy = gy + (float)p - 15.4f;
        float d = (float)(iy0 + yl) - cy;
        fy_s[yl][p] = expf(-(d * d) / SIG2) * den_y[p];
    }
    __syncthreads();

    // --- stage C: t[c][x][p] = sum_q Fx[x][q] * patch[c][p][q] ---
    for (int i = tid; i < NC * WIN * PH; i += 256) {
        int c = i / (WIN * PH);
        int r = i - c * (WIN * PH);
        int xl = r >> 5, p = r & 31;
        float acc = 0.f;
        #pragma unroll
        for (int q = 0; q < PW; ++q)
            acc += fx_s[xl][q] * patch_s[c][p][q];
        t_s[c][xl][p] = acc;
    }
    __syncthreads();

    // --- stage D: out[b][c][y][x] += (1/N) * sum_p Fy[y][p] * t[c][x][p] ---
    const float invN = 1.0f / (float)NN;
    const int b = blk >> 6;
    for (int i = tid; i < NC * WIN * WIN; i += 256) {
        int c = i / (WIN * WIN);
        int r = i - c * (WIN * WIN);
        int yl = r / WIN;
        int xl = r - yl * WIN;
        int ax = ix0 + xl;
        int ay = iy0 + yl;
        if (ax < 0 || ax >= IMG_W || ay < 0 || ay >= IMG_H) continue;
        float acc = 0.f;
        #pragma unroll
        for (int p = 0; p < PH; ++p)
            acc += fy_s[yl][p] * t_s[c][xl][p];
        atomicAdd(&out[(((size_t)b * NC + c) * IMG_H + ay) * IMG_W + ax], acc * invN);
    }
}

extern "C" void kernel_launch(void* const* d_in, const int* in_sizes, int n_in,
                              void* d_out, int out_size, void* d_ws, size_t ws_size,
                              hipStream_t stream) {
    const float* brushes = (const float*)d_in[0];   // (16, 64, 2) f32
    const float* patches = (const float*)d_in[1];   // (16, 64, 3, 32, 32) f32
    float* out = (float*)d_out;                     // (16, 3, 256, 256) f32
    float* gxy = (float*)d_ws;                      // 1024 * 2 floats scratch

    hipMemsetAsync(out, 0, (size_t)out_size * sizeof(float), stream);
    norm_kernel<<<NB, 64, 0, stream>>>(brushes, gxy);
    stroke_kernel<<<NB * NN, 256, 0, stream>>>(patches, gxy, out);
}

// Round 3
// 40.031 us; speedup vs baseline: 1.2578x; 1.2578x over previous
//
#include <hip/hip_runtime.h>

#define IMG_W 256
#define IMG_H 256
#define EPSN 1e-7f
#define SIG2 0.02f          // 2 * 0.1^2
#define INV_SIG2 (1.0f / SIG2)
#define NB 16               // batch
#define NN 64               // strokes per image
#define NC 3                // channels
#define PH 32
#define PW 32
#define WIN 36              // stroke footprint window (all nonzero f32 taps)
#define ROWP 36             // padded row stride (floats) -> 144B, 16B-aligned

// ---------------- kernel 0: fast zero fill (float4 grid) -------------------
__global__ __launch_bounds__(256)
void fill_zero(float4* __restrict__ out, int n4) {
    int i = blockIdx.x * 256 + threadIdx.x;
    if (i < n4) out[i] = make_float4(0.f, 0.f, 0.f, 0.f);
}

// ---------------- kernel 1: one block per stroke ---------------------------
// 128 threads (2 waves). Threads 0..107 own one (c, xl) pair and keep the
// Fx row and t row fully in registers. patch/fy LDS reads are uniform
// (multicast/broadcast) float4s -> near-zero bank conflicts.
__global__ __launch_bounds__(128)
void stroke_kernel(const float* __restrict__ brushes,
                   const float* __restrict__ patches,
                   float* __restrict__ out) {
    __shared__ float patch_s[NC][PH][ROWP];   // [c][p][q], rows 16B aligned
    __shared__ float fy_s[WIN][ROWP];         // [yl][p], includes den_y/N
    __shared__ float den_x[PW];
    __shared__ float den_y[PH];
    __shared__ float gxy_s[2];

    const int blk = blockIdx.x;               // stroke index b*64+n
    const int b   = blk >> 6;
    const int n   = blk & 63;
    const int tid = threadIdx.x;
    const float* P = patches + (size_t)blk * (NC * PH * PW);

    // --- fused per-image min/max normalization (wave 0) ---
    if (tid < 64) {
        float x = brushes[(b * NN + tid) * 2 + 0];
        float y = brushes[(b * NN + tid) * 2 + 1];
        float mnx = x, mxx = x, mny = y, mxy = y;
        #pragma unroll
        for (int off = 32; off > 0; off >>= 1) {
            mnx = fminf(mnx, __shfl_xor(mnx, off));
            mxx = fmaxf(mxx, __shfl_xor(mxx, off));
            mny = fminf(mny, __shfl_xor(mny, off));
            mxy = fmaxf(mxy, __shfl_xor(mxy, off));
        }
        if (tid == n) {
            gxy_s[0] = (x - mnx) / (mxx - mnx + EPSN) * (float)IMG_W;
            gxy_s[1] = (y - mny) / (mxy - mny + EPSN) * (float)IMG_H;
        }
    }

    // --- stage patch -> LDS (float4, rows padded to 16B alignment) ---
    for (int i = tid; i < NC * PH * PW / 4; i += 128) {
        float4 v = ((const float4*)P)[i];
        int base = i * 4;
        int c = base >> 10;                   // /1024
        int r = base & 1023;
        int p = r >> 5, q = r & 31;           // q % 4 == 0
        *(float4*)&patch_s[c][p][q] = v;
    }
    __syncthreads();

    const float gx = gxy_s[0];
    const float gy = gxy_s[1];
    const int ix0 = (int)floorf(gx) - 17;
    const int iy0 = (int)floorf(gy) - 17;

    // --- normalization denominators (4 taps hold all nonzero f32 terms) ---
    if (tid < PW) {
        float cx = gx + (float)tid - 15.5f;   // ux_q = gx + (q+1) - 16.5
        int f = (int)floorf(cx);
        float s = 0.f;
        #pragma unroll
        for (int t = -1; t <= 2; ++t) {
            int a = f + t;
            if (a >= -16 && a <= IMG_W + 15) {
                float d = (float)a - cx;
                s += expf(-(d * d) * INV_SIG2);
            }
        }
        den_x[tid] = 1.f / (s + EPSN);
    } else if (tid < 2 * PW) {
        int p = tid - PW;
        float cy = gy + (float)p - 15.4f;     // uy_p = gy + (p+1) - 16.4
        int f = (int)floorf(cy);
        float s = 0.f;
        #pragma unroll
        for (int t = -1; t <= 2; ++t) {
            int a = f + t;
            if (a >= -16 && a <= IMG_H + 15) {
                float d = (float)a - cy;
                s += expf(-(d * d) * INV_SIG2);
            }
        }
        den_y[p] = 1.f / (s + EPSN);
    }
    __syncthreads();

    // --- build Fy window in LDS (scaled by den_y and 1/N) ---
    for (int i = tid; i < WIN * PH; i += 128) {
        int yl = i >> 5, p = i & 31;
        float cy = gy + (float)p - 15.4f;
        float d = (float)(iy0 + yl) - cy;
        fy_s[yl][p] = expf(-(d * d) * INV_SIG2) * den_y[p] * (1.0f / (float)NN);
    }

    // --- per-thread Fx row in registers ---
    const int cc = tid / WIN;                 // channel
    const int xl = tid - cc * WIN;            // window column
    const bool active = (tid < NC * WIN);
    const int ax = ix0 + xl;

    float fx[PW];
    if (active) {
        #pragma unroll
        for (int q = 0; q < PW; ++q) {
            float d = (float)ax - (gx + (float)q - 15.5f);
            fx[q] = expf(-(d * d) * INV_SIG2) * den_x[q];
        }
    }
    __syncthreads();                          // fy_s ready

    if (!active || ax < 0 || ax >= IMG_W) return;  // after last sync: safe

    // --- stage C: t[p] = sum_q fx[q] * patch[c][p][q]  (regs) ---
    float t[PH];
    #pragma unroll
    for (int p = 0; p < PH; ++p) {
        const float4* row = (const float4*)&patch_s[cc][p][0];  // uniform addr (3 per wave)
        float a0 = 0.f, a1 = 0.f, a2 = 0.f, a3 = 0.f;
        #pragma unroll
        for (int q4 = 0; q4 < PW / 4; ++q4) {
            float4 v = row[q4];
            a0 += fx[q4 * 4 + 0] * v.x;
            a1 += fx[q4 * 4 + 1] * v.y;
            a2 += fx[q4 * 4 + 2] * v.z;
            a3 += fx[q4 * 4 + 3] * v.w;
        }
        t[p] = (a0 + a1) + (a2 + a3);
    }

    // --- stage D: out[b][c][ay][ax] += sum_p fy[yl][p] * t[p] ---
    float* outc = out + (((size_t)b * NC + cc) * IMG_H) * IMG_W + ax;
    for (int yl = 0; yl < WIN; ++yl) {
        int ay = iy0 + yl;
        if (ay < 0 || ay >= IMG_H) continue;
        const float4* fr = (const float4*)&fy_s[yl][0];         // broadcast addr
        float a0 = 0.f, a1 = 0.f, a2 = 0.f, a3 = 0.f;
        #pragma unroll
        for (int p4 = 0; p4 < PH / 4; ++p4) {
            float4 v = fr[p4];
            a0 += v.x * t[p4 * 4 + 0];
            a1 += v.y * t[p4 * 4 + 1];
            a2 += v.z * t[p4 * 4 + 2];
            a3 += v.w * t[p4 * 4 + 3];
        }
        atomicAdd(outc + (size_t)ay * IMG_W, (a0 + a1) + (a2 + a3));
    }
}

extern "C" void kernel_launch(void* const* d_in, const int* in_sizes, int n_in,
                              void* d_out, int out_size, void* d_ws, size_t ws_size,
                              hipStream_t stream) {
    const float* brushes = (const float*)d_in[0];   // (16, 64, 2) f32
    const float* patches = (const float*)d_in[1];   // (16, 64, 3, 32, 32) f32
    float* out = (float*)d_out;                     // (16, 3, 256, 256) f32

    int n4 = out_size / 4;                          // 786432 float4s
    fill_zero<<<(n4 + 255) / 256, 256, 0, stream>>>((float4*)out, n4);
    stroke_kernel<<<NB * NN, 128, 0, stream>>>(brushes, patches, out);
}